// Round 5
// baseline (742.010 us; speedup 1.0000x reference)
//
#include <hip/hip_runtime.h>
#include <hip/hip_cooperative_groups.h>

namespace cg = cooperative_groups;

#define N_NODES 50000
#define N_EDGES 800000
#define IN_DIM 100
#define OUT_DIM 40
#define ROW 50            // 50 dwords = 100 bf16 per node row (used)
#define ROW_PAD 64        // padded pitch: 256 B -> one row = 16 lanes x dwordx4
#define SCAN_B 512
#define NSCAN_BLK ((N_NODES + SCAN_B - 1) / SCAN_B)   // 98
#define CSR_CAP (N_EDGES + N_NODES * 8 + 64)          // aligned-degree worst case

typedef unsigned int uint;

// ---- bf16 helpers (packed pair in one dword) ----
__device__ __forceinline__ float bflo(uint u) { return __uint_as_float(u << 16); }
__device__ __forceinline__ float bfhi(uint u) { return __uint_as_float(u & 0xffff0000u); }
__device__ __forceinline__ uint packbf(float a, float b) {
    uint ua = __float_as_uint(a), ub = __float_as_uint(b);
    ua = (ua + 0x7fffu + ((ua >> 16) & 1u)) >> 16;      // RNE
    ub = (ub + 0x7fffu + ((ub >> 16) & 1u)) >> 16;
    return ua | (ub << 16);
}

// ---------------- zero scratch: {deg, colsum, colsq} + 3 zero pad-rows ----------------
__global__ void zero_kernel(int* p, int n, uint* fs, uint* bufA, uint* bufB) {
    int i = blockIdx.x * blockDim.x + threadIdx.x;
    if (i < n) p[i] = 0;
    if (i < ROW_PAD) {   // full 256B pad row (index N_NODES)
        fs[(size_t)N_NODES * ROW_PAD + i] = 0u;
        bufA[(size_t)N_NODES * ROW_PAD + i] = 0u;
        bufB[(size_t)N_NODES * ROW_PAD + i] = 0u;
    }
}

// ---------------- in-degree; keep returned old count as the edge's slot ----------------
__global__ void deg_kernel(const int* __restrict__ dst, int* __restrict__ deg,
                           int* __restrict__ eoff) {
    int e = blockIdx.x * blockDim.x + threadIdx.x;
    if (e < N_EDGES) eoff[e] = atomicAdd(&deg[dst[e]], 1);
}

// ---------------- scan phase 1: scan ALIGNED degrees ((d+7)&~7), emit norms ----
__global__ __launch_bounds__(SCAN_B) void scan1_kernel(const int* __restrict__ deg,
                                                       int* __restrict__ rowptr,
                                                       float* __restrict__ norm,
                                                       float* __restrict__ norm2,
                                                       int* __restrict__ blocksum) {
    int i = blockIdx.x * SCAN_B + threadIdx.x;
    int lane = threadIdx.x & 63, wid = threadIdx.x >> 6;
    int d = (i < N_NODES) ? deg[i] : 0;
    int da = (d + 7) & ~7;          // pad each node's edge list to multiple of 8
    int v = da;
#pragma unroll
    for (int off = 1; off < 64; off <<= 1) {
        int t = __shfl_up(v, off);
        if (lane >= off) v += t;
    }
    __shared__ int wsum[8];
    if (lane == 63) wsum[wid] = v;
    __syncthreads();
    if (threadIdx.x < 8) {
        int w = wsum[threadIdx.x];
#pragma unroll
        for (int off = 1; off < 8; off <<= 1) {
            int t = __shfl_up(w, off);
            if (lane >= off) w += t;
        }
        wsum[threadIdx.x] = w;
    }
    __syncthreads();
    int woff = wid ? wsum[wid - 1] : 0;
    int incl = woff + v;
    if (i < N_NODES) {
        rowptr[i] = incl - da;
        float n1 = 1.0f / sqrtf((float)max(d, 1));
        norm[i] = n1;
        norm2[i] = n1 * n1;
    }
    if (threadIdx.x == SCAN_B - 1) blocksum[blockIdx.x] = incl;
}

// ---------------- scan phase 2 ----------------
__global__ __launch_bounds__(128) void scan2_kernel(const int* __restrict__ blocksum,
                                                    int* __restrict__ blockoff,
                                                    int* __restrict__ rowptr) {
    __shared__ int s[128];
    int t = threadIdx.x;
    int v = (t < NSCAN_BLK) ? blocksum[t] : 0;
    s[t] = v;
    __syncthreads();
    for (int off = 1; off < 128; off <<= 1) {
        int u = (t >= off) ? s[t - off] : 0;
        __syncthreads();
        s[t] += u;
        __syncthreads();
    }
    if (t < NSCAN_BLK) blockoff[t] = s[t] - v;
    if (t == 127) rowptr[N_NODES] = s[127];
}

// ---------------- scan phase 3: finalize rowptr + fill CSR pad slots ----------------
__global__ __launch_bounds__(SCAN_B) void scan3_kernel(int* __restrict__ rowptr,
                                                       const int* __restrict__ blockoff,
                                                       const int* __restrict__ deg,
                                                       int* __restrict__ csr) {
    int i = blockIdx.x * SCAN_B + threadIdx.x;
    if (i < N_NODES) {
        int rp = rowptr[i] + blockoff[blockIdx.x];
        rowptr[i] = rp;
        int d = deg[i], da = (d + 7) & ~7;
        for (int k = d; k < da; ++k) csr[rp + k] = N_NODES;   // dummy -> zero row
    }
}

// ---------------- CSR scatter, atomic-free (slot precomputed in eoff) ----------------
__global__ void csr_fill_kernel(const int* __restrict__ src, const int* __restrict__ dst,
                                const int* __restrict__ rowptr,
                                const int* __restrict__ eoff,
                                int* __restrict__ csr) {
    int e = blockIdx.x * blockDim.x + threadIdx.x;
    if (e < N_EDGES) csr[rowptr[dst[e]] + eoff[e]] = src[e];
}

// ================= fused middle: prescale -> hop1 -> hop2 -> hop3 -> col_stats =========
// One cooperative kernel; grid.sync() between phases removes 4 launch/drain
// boundaries. Round-4 lesson: WITHOUT a min-waves hint the allocator chased
// 32 waves/CU at 28 VGPRs and serialized the 4-deep gather pipeline (1020us,
// VALUBusy 4%). __launch_bounds__(256, 4) = 4 blocks/CU -> 128 VGPR budget,
// 16 waves/CU: enough registers for 4 uint4 gathers in flight per wave
// (the round-1/2-proven MLP), still enough waves to hide latency.

__device__ __forceinline__ void spmm_phase(const uint4* __restrict__ H4,
                                           const int* __restrict__ rowptr,
                                           const int* __restrict__ csr,
                                           const float* __restrict__ scale,
                                           uint4* __restrict__ out4,
                                           int waveId, int nWaves) {
    const int l = threadIdx.x & 63;
    const int q = l >> 4;          // quarter 0..3
    const int ql = l & 15;         // lane within quarter
    for (int n = waveId; n < N_NODES; n += nWaves) {
        const int beg = rowptr[n], end = rowptr[n + 1];   // multiple-of-8 span
        float ax0 = 0.f, ax1 = 0.f, ax2 = 0.f, ax3 = 0.f;
        float ay0 = 0.f, ay1 = 0.f, ay2 = 0.f, ay3 = 0.f;
        int j = beg;
        for (; j + 16 <= end; j += 16) {
            int s0 = csr[j + q];
            int s1 = csr[j + 4 + q];
            int s2 = csr[j + 8 + q];
            int s3 = csr[j + 12 + q];
            uint4 u0 = H4[(size_t)s0 * 16 + ql];
            uint4 u1 = H4[(size_t)s1 * 16 + ql];
            uint4 u2 = H4[(size_t)s2 * 16 + ql];
            uint4 u3 = H4[(size_t)s3 * 16 + ql];
            ax0 += bflo(u0.x); ay0 += bfhi(u0.x);
            ax1 += bflo(u0.y); ay1 += bfhi(u0.y);
            ax2 += bflo(u0.z); ay2 += bfhi(u0.z);
            ax3 += bflo(u0.w); ay3 += bfhi(u0.w);
            ax0 += bflo(u1.x); ay0 += bfhi(u1.x);
            ax1 += bflo(u1.y); ay1 += bfhi(u1.y);
            ax2 += bflo(u1.z); ay2 += bfhi(u1.z);
            ax3 += bflo(u1.w); ay3 += bfhi(u1.w);
            ax0 += bflo(u2.x); ay0 += bfhi(u2.x);
            ax1 += bflo(u2.y); ay1 += bfhi(u2.y);
            ax2 += bflo(u2.z); ay2 += bfhi(u2.z);
            ax3 += bflo(u2.w); ay3 += bfhi(u2.w);
            ax0 += bflo(u3.x); ay0 += bfhi(u3.x);
            ax1 += bflo(u3.y); ay1 += bfhi(u3.y);
            ax2 += bflo(u3.z); ay2 += bfhi(u3.z);
            ax3 += bflo(u3.w); ay3 += bfhi(u3.w);
        }
        if (j < end) {                 // 8-edge tail
            int s0 = csr[j + q];
            int s1 = csr[j + 4 + q];
            uint4 u0 = H4[(size_t)s0 * 16 + ql];
            uint4 u1 = H4[(size_t)s1 * 16 + ql];
            ax0 += bflo(u0.x); ay0 += bfhi(u0.x);
            ax1 += bflo(u0.y); ay1 += bfhi(u0.y);
            ax2 += bflo(u0.z); ay2 += bfhi(u0.z);
            ax3 += bflo(u0.w); ay3 += bfhi(u0.w);
            ax0 += bflo(u1.x); ay0 += bfhi(u1.x);
            ax1 += bflo(u1.y); ay1 += bfhi(u1.y);
            ax2 += bflo(u1.z); ay2 += bfhi(u1.z);
            ax3 += bflo(u1.w); ay3 += bfhi(u1.w);
        }
        // reduce the 4 quarters (lanes l ^ 16 ^ 32)
        ax0 += __shfl_xor(ax0, 16); ax1 += __shfl_xor(ax1, 16);
        ax2 += __shfl_xor(ax2, 16); ax3 += __shfl_xor(ax3, 16);
        ay0 += __shfl_xor(ay0, 16); ay1 += __shfl_xor(ay1, 16);
        ay2 += __shfl_xor(ay2, 16); ay3 += __shfl_xor(ay3, 16);
        ax0 += __shfl_xor(ax0, 32); ax1 += __shfl_xor(ax1, 32);
        ax2 += __shfl_xor(ax2, 32); ax3 += __shfl_xor(ax3, 32);
        ay0 += __shfl_xor(ay0, 32); ay1 += __shfl_xor(ay1, 32);
        ay2 += __shfl_xor(ay2, 32); ay3 += __shfl_xor(ay3, 32);
        if (q == 0) {
            float sc = scale[n];
            uint4 o;
            o.x = packbf(ax0 * sc, ay0 * sc);
            o.y = packbf(ax1 * sc, ay1 * sc);
            o.z = packbf(ax2 * sc, ay2 * sc);
            o.w = packbf(ax3 * sc, ay3 * sc);
            out4[(size_t)n * 16 + ql] = o;   // full row incl. zero pads
        }
    }
}

__global__ __launch_bounds__(256, 4) void fused_mid_kernel(const float* __restrict__ feat,
                                                           const float* __restrict__ norm,
                                                           const float* __restrict__ norm2,
                                                           const int* __restrict__ rowptr,
                                                           const int* __restrict__ csr,
                                                           uint4* __restrict__ fs4,
                                                           uint4* __restrict__ bufA4,
                                                           uint4* __restrict__ bufB4,
                                                           float* __restrict__ colsum,
                                                           float* __restrict__ colsq) {
    cg::grid_group grid = cg::this_grid();
    const int gt = blockIdx.x * 256 + threadIdx.x;
    const int gsz = gridDim.x * 256;

    // ---- phase 0: prescale fs = bf16(norm ⊙ feat), padded rows ----
    for (int t = gt; t < N_NODES * 16; t += gsz) {
        int n = t >> 4, ql = t & 15;
        float nm = norm[n];
        uint4 o = make_uint4(0u, 0u, 0u, 0u);
        const float4* fr = (const float4*)(feat + (size_t)n * IN_DIM);
        if (ql < 12) {
            float4 a = fr[2 * ql], b2 = fr[2 * ql + 1];
            o.x = packbf(a.x * nm, a.y * nm);  o.y = packbf(a.z * nm, a.w * nm);
            o.z = packbf(b2.x * nm, b2.y * nm); o.w = packbf(b2.z * nm, b2.w * nm);
        } else if (ql == 12) {
            float4 a = fr[24];                 // features 96..99
            o.x = packbf(a.x * nm, a.y * nm);  o.y = packbf(a.z * nm, a.w * nm);
        }
        fs4[t] = o;
    }
    grid.sync();

    // ---- phases 1-3: three hops ----
    const int waveId = blockIdx.x * 4 + (threadIdx.x >> 6);
    const int nWaves = gridDim.x * 4;
    spmm_phase(fs4,   rowptr, csr, norm2, bufA4, waveId, nWaves);
    grid.sync();
    spmm_phase(bufA4, rowptr, csr, norm2, bufB4, waveId, nWaves);
    grid.sync();
    spmm_phase(bufB4, rowptr, csr, norm,  bufA4, waveId, nWaves);
    grid.sync();

    // ---- phase 4: column stats over padded bf16 h3 (in bufA) ----
    {
        const uint* h = (const uint*)bufA4;
        const int total = N_NODES * ROW_PAD;   // stride gsz is a multiple of 64
        float s0 = 0.f, s1 = 0.f, q0 = 0.f, q1 = 0.f;
        for (int i = gt; i < total; i += gsz) {   // pads are zero, harmless
            uint u = h[i];
            float a = bflo(u), b = bfhi(u);
            s0 += a; s1 += b; q0 += a * a; q1 += b * b;
        }
        __shared__ float ssum[IN_DIM], ssq[IN_DIM];
        if (threadIdx.x < IN_DIM) { ssum[threadIdx.x] = 0.f; ssq[threadIdx.x] = 0.f; }
        __syncthreads();
        int p = gt & 63;   // fixed dword slot per thread (stride % 64 == 0)
        if (p < ROW) {
            atomicAdd(&ssum[2 * p], s0);
            atomicAdd(&ssum[2 * p + 1], s1);
            atomicAdd(&ssq[2 * p], q0);
            atomicAdd(&ssq[2 * p + 1], q1);
        }
        __syncthreads();
        if (threadIdx.x < IN_DIM) {
            atomicAdd(&colsum[threadIdx.x], ssum[threadIdx.x]);
            atomicAdd(&colsq[threadIdx.x], ssq[threadIdx.x]);
        }
    }
}

// ---------------- fold standardize into W,b ----------------
__global__ __launch_bounds__(256) void prep_kernel(const float* __restrict__ colsum,
                                                   const float* __restrict__ colsq,
                                                   const float* __restrict__ W,
                                                   const float* __restrict__ b,
                                                   float* __restrict__ Wt,
                                                   float* __restrict__ bp) {
    __shared__ float smean[IN_DIM];
    __shared__ float sinv[IN_DIM];
    int t = threadIdx.x;
    const float Nf = (float)N_NODES;
    if (t < IN_DIM) {
        float m = colsum[t] / Nf;
        float var = (colsq[t] - Nf * m * m) / (Nf - 1.0f);
        var = fmaxf(var, 1e-20f);
        smean[t] = m;
        sinv[t] = 1.0f / sqrtf(var);
    }
    __syncthreads();
    for (int i = t; i < IN_DIM * OUT_DIM; i += 256) {
        int o = i % OUT_DIM, f = i / OUT_DIM;
        Wt[f * OUT_DIM + o] = W[o * IN_DIM + f] * sinv[f];
    }
    if (t < OUT_DIM) {
        float acc = b[t];
        for (int f = 0; f < IN_DIM; ++f)
            acc -= smean[f] * W[t * IN_DIM + f] * sinv[f];
        bp[t] = acc;
    }
}

// ---------------- final linear: 10 threads/node, uint4 row reads, W' in LDS ----
__global__ __launch_bounds__(256) void final_kernel(const uint4* __restrict__ h4,
                                                    const float* __restrict__ Wt,
                                                    const float* __restrict__ bp,
                                                    float* __restrict__ out) {
    __shared__ float sW[104 * OUT_DIM];   // 16.25 KB
    __shared__ float sb[OUT_DIM];
    for (int i = threadIdx.x; i < 104 * OUT_DIM; i += 256)
        sW[i] = (i < IN_DIM * OUT_DIM) ? Wt[i] : 0.f;
    if (threadIdx.x < OUT_DIM) sb[threadIdx.x] = bp[threadIdx.x];
    __syncthreads();
    int t = blockIdx.x * 256 + threadIdx.x;
    if (t >= N_NODES * 10) return;
    int n = t / 10;
    int og = (t - n * 10) * 4;            // output group of 4
    const uint4* hr = h4 + (size_t)n * 16;
    float a0 = sb[og], a1 = sb[og + 1], a2 = sb[og + 2], a3 = sb[og + 3];
#pragma unroll
    for (int r = 0; r < 13; ++r) {        // dwords 0..51 (50,51 are zero pads)
        uint4 u = hr[r];
        int f = r * 8;
        float v0 = bflo(u.x), v1 = bfhi(u.x), v2 = bflo(u.y), v3 = bfhi(u.y);
        float v4 = bflo(u.z), v5 = bfhi(u.z), v6 = bflo(u.w), v7 = bfhi(u.w);
        const float* w0 = &sW[(f + 0) * OUT_DIM + og];
        const float* w1 = &sW[(f + 1) * OUT_DIM + og];
        const float* w2 = &sW[(f + 2) * OUT_DIM + og];
        const float* w3 = &sW[(f + 3) * OUT_DIM + og];
        const float* w4 = &sW[(f + 4) * OUT_DIM + og];
        const float* w5 = &sW[(f + 5) * OUT_DIM + og];
        const float* w6 = &sW[(f + 6) * OUT_DIM + og];
        const float* w7 = &sW[(f + 7) * OUT_DIM + og];
        a0 += v0 * w0[0] + v1 * w1[0] + v2 * w2[0] + v3 * w3[0]
            + v4 * w4[0] + v5 * w5[0] + v6 * w6[0] + v7 * w7[0];
        a1 += v0 * w0[1] + v1 * w1[1] + v2 * w2[1] + v3 * w3[1]
            + v4 * w4[1] + v5 * w5[1] + v6 * w6[1] + v7 * w7[1];
        a2 += v0 * w0[2] + v1 * w1[2] + v2 * w2[2] + v3 * w3[2]
            + v4 * w4[2] + v5 * w5[2] + v6 * w6[2] + v7 * w7[2];
        a3 += v0 * w0[3] + v1 * w1[3] + v2 * w2[3] + v3 * w3[3]
            + v4 * w4[3] + v5 * w5[3] + v6 * w6[3] + v7 * w7[3];
    }
    float4 o = make_float4(a0, a1, a2, a3);
    *((float4*)(out + (size_t)n * OUT_DIM + og)) = o;
}

extern "C" void kernel_launch(void* const* d_in, const int* in_sizes, int n_in,
                              void* d_out, int out_size, void* d_ws, size_t ws_size,
                              hipStream_t stream) {
    const float* feat = (const float*)d_in[0];   // [50000,100]
    const float* W    = (const float*)d_in[1];   // [40,100]
    const float* b    = (const float*)d_in[2];   // [40]
    const int*   src  = (const int*)d_in[3];     // [800000]
    const int*   dst  = (const int*)d_in[4];     // [800000]
    float* out = (float*)d_out;                  // [50000,40]

    char* w = (char*)d_ws;
    int*   deg      = (int*)w;    w += N_NODES * 4;
    float* colsum   = (float*)w;  w += 128 * 4;
    float* colsq    = (float*)w;  w += 128 * 4;
    // ---- end of zero region: (N_NODES + 256) ints ----
    int*   eoff     = (int*)w;    w += N_EDGES * 4;
    int*   rowptr   = (int*)w;    w += 50004 * 4;
    float* norm     = (float*)w;  w += N_NODES * 4;
    float* norm2    = (float*)w;  w += N_NODES * 4;
    int*   blocksum = (int*)w;    w += 128 * 4;
    int*   blockoff = (int*)w;    w += 128 * 4;
    int*   csr      = (int*)w;    w += CSR_CAP * 4;
    float* Wt       = (float*)w;  w += IN_DIM * OUT_DIM * 4;
    float* bp       = (float*)w;  w += 64 * 4;
    // align row buffers to 256 B
    w = (char*)(((size_t)w + 255) & ~(size_t)255);
    const size_t HB = (size_t)(N_NODES + 1) * ROW_PAD * 4;   // padded rows + zero row
    uint*  fs       = (uint*)w;   w += HB;
    uint*  bufA     = (uint*)w;   w += HB;
    uint*  bufB     = (uint*)w;   w += HB;

    // 1. zero {deg, colsum, colsq} + zero pad-rows
    {
        int nz = N_NODES + 256;
        zero_kernel<<<(nz + 255) / 256, 256, 0, stream>>>(deg, nz, fs, bufA, bufB);
    }
    // 2. in-degree + per-edge slot (single atomic per edge total)
    deg_kernel<<<(N_EDGES + 255) / 256, 256, 0, stream>>>(dst, deg, eoff);
    // 3. rowptr over 8-aligned degrees + norm/norm2; scan3 also fills CSR pad slots
    scan1_kernel<<<NSCAN_BLK, SCAN_B, 0, stream>>>(deg, rowptr, norm, norm2, blocksum);
    scan2_kernel<<<1, 128, 0, stream>>>(blocksum, blockoff, rowptr);
    scan3_kernel<<<NSCAN_BLK, SCAN_B, 0, stream>>>(rowptr, blockoff, deg, csr);
    // 4. CSR scatter (no atomics)
    csr_fill_kernel<<<(N_EDGES + 255) / 256, 256, 0, stream>>>(src, dst, rowptr, eoff, csr);
    // 5-7. fused cooperative middle: prescale + 3 hops + col_stats
    {
        static int maxBlkPerCU = 0;
        if (maxBlkPerCU == 0) {
            hipOccupancyMaxActiveBlocksPerMultiprocessor(&maxBlkPerCU,
                (const void*)fused_mid_kernel, 256, 0);
            if (maxBlkPerCU <= 0) maxBlkPerCU = 2;   // conservative fallback
        }
        int grid = maxBlkPerCU * 256;                 // 256 CUs
        if (grid > 2048) grid = 2048;
        uint4* fs4   = (uint4*)fs;
        uint4* bufA4 = (uint4*)bufA;
        uint4* bufB4 = (uint4*)bufB;
        void* args[] = { (void*)&feat, (void*)&norm, (void*)&norm2,
                         (void*)&rowptr, (void*)&csr,
                         (void*)&fs4, (void*)&bufA4, (void*)&bufB4,
                         (void*)&colsum, (void*)&colsq };
        hipLaunchCooperativeKernel((const void*)fused_mid_kernel,
                                   dim3(grid), dim3(256), args, 0, stream);
    }
    // 8. fold mean/std into W', b'
    prep_kernel<<<1, 256, 0, stream>>>(colsum, colsq, W, b, Wt, bp);
    // 9. final linear (10 threads per node)
    {
        int total = N_NODES * 10;
        final_kernel<<<(total + 255) / 256, 256, 0, stream>>>((const uint4*)bufA, Wt, bp, out);
    }
}

// Round 6
// 319.681 us; speedup vs baseline: 2.3211x; 2.3211x over previous
//
#include <hip/hip_runtime.h>

#define N_NODES 50000
#define N_EDGES 800000
#define IN_DIM 100
#define OUT_DIM 40
#define ROW 50            // 50 dwords = 100 bf16 per node row (used)
#define ROW_PAD 64        // padded pitch: 256 B -> one row = 16 lanes x dwordx4
#define SCAN_B 512
#define NSCAN_BLK ((N_NODES + SCAN_B - 1) / SCAN_B)   // 98
#define CSR_CAP (N_EDGES + N_NODES * 16 + 64)         // two 8-aligned segments per node
#define SHARD_SPLIT (N_NODES / 2)                     // src < 25000 -> shard 0

typedef unsigned int uint;
typedef float f4 __attribute__((ext_vector_type(4)));

// ---- bf16 helpers (packed pair in one dword) ----
__device__ __forceinline__ float bflo(uint u) { return __uint_as_float(u << 16); }
__device__ __forceinline__ float bfhi(uint u) { return __uint_as_float(u & 0xffff0000u); }
__device__ __forceinline__ uint packbf(float a, float b) {
    uint ua = __float_as_uint(a), ub = __float_as_uint(b);
    ua = (ua + 0x7fffu + ((ua >> 16) & 1u)) >> 16;      // RNE
    ub = (ub + 0x7fffu + ((ub >> 16) & 1u)) >> 16;
    return ua | (ub << 16);
}

// ---------------- zero scratch: {deg2, colsum, colsq} + 3 zero pad-rows ----------------
__global__ void zero_kernel(int* p, int n, uint* fs, uint* bufA, uint* bufB) {
    int i = blockIdx.x * blockDim.x + threadIdx.x;
    if (i < n) p[i] = 0;
    if (i < ROW_PAD) {   // full 256B pad row (index N_NODES)
        fs[(size_t)N_NODES * ROW_PAD + i] = 0u;
        bufA[(size_t)N_NODES * ROW_PAD + i] = 0u;
        bufB[(size_t)N_NODES * ROW_PAD + i] = 0u;
    }
}

// -------- per-(dst,shard) in-degree; returned old count = slot within segment --------
__global__ void deg_kernel(const int* __restrict__ src, const int* __restrict__ dst,
                           int* __restrict__ deg2, int* __restrict__ eoff) {
    int e = blockIdx.x * blockDim.x + threadIdx.x;
    if (e < N_EDGES) {
        int s = (src[e] >= SHARD_SPLIT) ? 1 : 0;
        eoff[e] = atomicAdd(&deg2[2 * dst[e] + s], 1);
    }
}

// ---- scan phase 1: scan ALIGNED total degree (align8(d0)+align8(d1)), emit norms ----
__global__ __launch_bounds__(SCAN_B) void scan1_kernel(const int* __restrict__ deg2,
                                                       int* __restrict__ rowptr,
                                                       float* __restrict__ norm,
                                                       float* __restrict__ norm2,
                                                       int* __restrict__ blocksum) {
    int i = blockIdx.x * SCAN_B + threadIdx.x;
    int lane = threadIdx.x & 63, wid = threadIdx.x >> 6;
    int d0 = (i < N_NODES) ? deg2[2 * i] : 0;
    int d1 = (i < N_NODES) ? deg2[2 * i + 1] : 0;
    int d = d0 + d1;
    int da = ((d0 + 7) & ~7) + ((d1 + 7) & ~7);   // both segments 8-aligned
    int v = da;
#pragma unroll
    for (int off = 1; off < 64; off <<= 1) {
        int t = __shfl_up(v, off);
        if (lane >= off) v += t;
    }
    __shared__ int wsum[8];
    if (lane == 63) wsum[wid] = v;
    __syncthreads();
    if (threadIdx.x < 8) {
        int w = wsum[threadIdx.x];
#pragma unroll
        for (int off = 1; off < 8; off <<= 1) {
            int t = __shfl_up(w, off);
            if (lane >= off) w += t;
        }
        wsum[threadIdx.x] = w;
    }
    __syncthreads();
    int woff = wid ? wsum[wid - 1] : 0;
    int incl = woff + v;
    if (i < N_NODES) {
        rowptr[i] = incl - da;
        float n1 = 1.0f / sqrtf((float)max(d, 1));
        norm[i] = n1;
        norm2[i] = n1 * n1;
    }
    if (threadIdx.x == SCAN_B - 1) blocksum[blockIdx.x] = incl;
}

// ---------------- scan phase 2 ----------------
__global__ __launch_bounds__(128) void scan2_kernel(const int* __restrict__ blocksum,
                                                    int* __restrict__ blockoff,
                                                    int* __restrict__ rowptr) {
    __shared__ int s[128];
    int t = threadIdx.x;
    int v = (t < NSCAN_BLK) ? blocksum[t] : 0;
    s[t] = v;
    __syncthreads();
    for (int off = 1; off < 128; off <<= 1) {
        int u = (t >= off) ? s[t - off] : 0;
        __syncthreads();
        s[t] += u;
        __syncthreads();
    }
    if (t < NSCAN_BLK) blockoff[t] = s[t] - v;
    if (t == 127) rowptr[N_NODES] = s[127];
}

// -------- scan phase 3: finalize rowptr + fill pad slots of BOTH segments --------
__global__ __launch_bounds__(SCAN_B) void scan3_kernel(int* __restrict__ rowptr,
                                                       const int* __restrict__ blockoff,
                                                       const int* __restrict__ deg2,
                                                       int* __restrict__ csr) {
    int i = blockIdx.x * SCAN_B + threadIdx.x;
    if (i < N_NODES) {
        int rp = rowptr[i] + blockoff[blockIdx.x];
        rowptr[i] = rp;
        int d0 = deg2[2 * i], d1 = deg2[2 * i + 1];
        int da0 = (d0 + 7) & ~7, da1 = (d1 + 7) & ~7;
        for (int k = d0; k < da0; ++k) csr[rp + k] = N_NODES;          // dummy -> zero row
        for (int k = d1; k < da1; ++k) csr[rp + da0 + k] = N_NODES;
    }
}

// ---------------- CSR scatter into shard segments (slot precomputed in eoff) ----------
__global__ void csr_fill_kernel(const int* __restrict__ src, const int* __restrict__ dst,
                                const int* __restrict__ rowptr,
                                const int* __restrict__ deg2,
                                const int* __restrict__ eoff,
                                int* __restrict__ csr) {
    int e = blockIdx.x * blockDim.x + threadIdx.x;
    if (e < N_EDGES) {
        int d = dst[e];
        int sv = src[e];
        int base = rowptr[d];
        if (sv >= SHARD_SPLIT) base += (deg2[2 * d] + 7) & ~7;   // skip segment 0
        csr[base + eoff[e]] = sv;
    }
}

// ---------------- pre-scale: fs = bf16(norm ⊙ feat), full padded rows, uint4 ----
__global__ __launch_bounds__(256) void prescale_kernel(const float* __restrict__ feat,
                                                       const float* __restrict__ norm,
                                                       uint4* __restrict__ fs4) {
    int t = blockIdx.x * 256 + threadIdx.x;   // N_NODES*16 threads
    if (t >= N_NODES * 16) return;
    int n = t >> 4, ql = t & 15;
    float nm = norm[n];
    uint4 o = make_uint4(0u, 0u, 0u, 0u);
    const float4* fr = (const float4*)(feat + (size_t)n * IN_DIM);
    if (ql < 12) {
        float4 a = fr[2 * ql], b2 = fr[2 * ql + 1];
        o.x = packbf(a.x * nm, a.y * nm);  o.y = packbf(a.z * nm, a.w * nm);
        o.z = packbf(b2.x * nm, b2.y * nm); o.w = packbf(b2.z * nm, b2.w * nm);
    } else if (ql == 12) {
        float4 a = fr[24];                 // features 96..99
        o.x = packbf(a.x * nm, a.y * nm);  o.y = packbf(a.z * nm, a.w * nm);
    }
    fs4[t] = o;
}

// ============ SGC hop, src-sharded two-pass ============
// Pass A gathers only shard-0 rows (contiguous 6.4 MB of H -> much better per-XCD
// L2 residency than the full 12.8 MB) into an f32 accumulator written with
// NONTEMPORAL stores (keeps the stream out of L2). Pass B gathers shard-1 rows,
// NT-loads the accumulator, adds, scales, packs bf16. Request count per hop is
// unchanged vs the single-pass baseline (2 lines/edge), and each WAVE processes
// TWO nodes interleaved so the ~8-edge segments still keep 4 row-gathers in
// flight (round-1/2 A/B: dropping below ~4 in-flight costs 25%).
// Accumulator layout: accum[n*128 + dword*2 + {0,1}] (f32 per bf16 feature slot).

#define GATHER2(jj, ee, sX, sY)                                            \
    int sX = (jj < ee) ? csr[jj + q] : (int)N_NODES;                       \
    int sY = (jj < ee) ? csr[jj + 4 + q] : (int)N_NODES;

#define ACC8(u, x0, y0, x1, y1, x2, y2, x3, y3)                            \
    x0 += bflo(u.x); y0 += bfhi(u.x);                                      \
    x1 += bflo(u.y); y1 += bfhi(u.y);                                      \
    x2 += bflo(u.z); y2 += bfhi(u.z);                                      \
    x3 += bflo(u.w); y3 += bfhi(u.w);

#define RED8(x0, y0, x1, y1, x2, y2, x3, y3, m)                            \
    x0 += __shfl_xor(x0, m); y0 += __shfl_xor(y0, m);                      \
    x1 += __shfl_xor(x1, m); y1 += __shfl_xor(y1, m);                      \
    x2 += __shfl_xor(x2, m); y2 += __shfl_xor(y2, m);                      \
    x3 += __shfl_xor(x3, m); y3 += __shfl_xor(y3, m);

__global__ __launch_bounds__(128) void spmmA_kernel(const uint4* __restrict__ H4,
                                                    const int* __restrict__ rowptr,
                                                    const int* __restrict__ deg2,
                                                    const int* __restrict__ csr,
                                                    float* __restrict__ accum) {
    const int wave = threadIdx.x >> 6;
    const int n0 = (blockIdx.x * 2 + wave) * 2;
    const int n1 = n0 + 1;
    const int l = threadIdx.x & 63;
    const int q = l >> 4, ql = l & 15;
    int j0 = rowptr[n0], e0 = j0 + ((deg2[2 * n0] + 7) & ~7);
    int j1 = rowptr[n1], e1 = j1 + ((deg2[2 * n1] + 7) & ~7);
    float ax0 = 0.f, ay0 = 0.f, ax1 = 0.f, ay1 = 0.f,
          ax2 = 0.f, ay2 = 0.f, ax3 = 0.f, ay3 = 0.f;   // node n0
    float bx0 = 0.f, by0 = 0.f, bx1 = 0.f, by1 = 0.f,
          bx2 = 0.f, by2 = 0.f, bx3 = 0.f, by3 = 0.f;   // node n1
    while (j0 < e0 || j1 < e1) {
        GATHER2(j0, e0, sA0, sA1)
        GATHER2(j1, e1, sB0, sB1)
        uint4 u0 = H4[(size_t)sA0 * 16 + ql];
        uint4 u1 = H4[(size_t)sA1 * 16 + ql];
        uint4 u2 = H4[(size_t)sB0 * 16 + ql];
        uint4 u3 = H4[(size_t)sB1 * 16 + ql];
        ACC8(u0, ax0, ay0, ax1, ay1, ax2, ay2, ax3, ay3)
        ACC8(u1, ax0, ay0, ax1, ay1, ax2, ay2, ax3, ay3)
        ACC8(u2, bx0, by0, bx1, by1, bx2, by2, bx3, by3)
        ACC8(u3, bx0, by0, bx1, by1, bx2, by2, bx3, by3)
        j0 += 8; j1 += 8;
    }
    RED8(ax0, ay0, ax1, ay1, ax2, ay2, ax3, ay3, 16)
    RED8(ax0, ay0, ax1, ay1, ax2, ay2, ax3, ay3, 32)
    RED8(bx0, by0, bx1, by1, bx2, by2, bx3, by3, 16)
    RED8(bx0, by0, bx1, by1, bx2, by2, bx3, by3, 32)
    if (q == 0) {
        float* p = accum + (size_t)n0 * 128 + ql * 8;
        f4 v0 = {ax0, ay0, ax1, ay1};
        f4 v1 = {ax2, ay2, ax3, ay3};
        __builtin_nontemporal_store(v0, (f4*)p);
        __builtin_nontemporal_store(v1, (f4*)(p + 4));
    } else if (q == 1) {
        float* p = accum + (size_t)n1 * 128 + ql * 8;
        f4 v0 = {bx0, by0, bx1, by1};
        f4 v1 = {bx2, by2, bx3, by3};
        __builtin_nontemporal_store(v0, (f4*)p);
        __builtin_nontemporal_store(v1, (f4*)(p + 4));
    }
}

__global__ __launch_bounds__(128) void spmmB_kernel(const uint4* __restrict__ H4,
                                                    const int* __restrict__ rowptr,
                                                    const int* __restrict__ deg2,
                                                    const int* __restrict__ csr,
                                                    const float* __restrict__ accum,
                                                    const float* __restrict__ scale,
                                                    uint4* __restrict__ out4) {
    const int wave = threadIdx.x >> 6;
    const int n0 = (blockIdx.x * 2 + wave) * 2;
    const int n1 = n0 + 1;
    const int l = threadIdx.x & 63;
    const int q = l >> 4, ql = l & 15;
    int rp0 = rowptr[n0], rp1 = rowptr[n1];
    int da00 = (deg2[2 * n0] + 7) & ~7, da10 = (deg2[2 * n1] + 7) & ~7;
    int j0 = rp0 + da00, e0 = j0 + ((deg2[2 * n0 + 1] + 7) & ~7);
    int j1 = rp1 + da10, e1 = j1 + ((deg2[2 * n1 + 1] + 7) & ~7);
    float ax0 = 0.f, ay0 = 0.f, ax1 = 0.f, ay1 = 0.f,
          ax2 = 0.f, ay2 = 0.f, ax3 = 0.f, ay3 = 0.f;
    float bx0 = 0.f, by0 = 0.f, bx1 = 0.f, by1 = 0.f,
          bx2 = 0.f, by2 = 0.f, bx3 = 0.f, by3 = 0.f;
    while (j0 < e0 || j1 < e1) {
        GATHER2(j0, e0, sA0, sA1)
        GATHER2(j1, e1, sB0, sB1)
        uint4 u0 = H4[(size_t)sA0 * 16 + ql];
        uint4 u1 = H4[(size_t)sA1 * 16 + ql];
        uint4 u2 = H4[(size_t)sB0 * 16 + ql];
        uint4 u3 = H4[(size_t)sB1 * 16 + ql];
        ACC8(u0, ax0, ay0, ax1, ay1, ax2, ay2, ax3, ay3)
        ACC8(u1, ax0, ay0, ax1, ay1, ax2, ay2, ax3, ay3)
        ACC8(u2, bx0, by0, bx1, by1, bx2, by2, bx3, by3)
        ACC8(u3, bx0, by0, bx1, by1, bx2, by2, bx3, by3)
        j0 += 8; j1 += 8;
    }
    RED8(ax0, ay0, ax1, ay1, ax2, ay2, ax3, ay3, 16)
    RED8(ax0, ay0, ax1, ay1, ax2, ay2, ax3, ay3, 32)
    RED8(bx0, by0, bx1, by1, bx2, by2, bx3, by3, 16)
    RED8(bx0, by0, bx1, by1, bx2, by2, bx3, by3, 32)
    if (q == 0) {
        const float* p = accum + (size_t)n0 * 128 + ql * 8;
        f4 w0 = __builtin_nontemporal_load((const f4*)p);
        f4 w1 = __builtin_nontemporal_load((const f4*)(p + 4));
        float sc = scale[n0];
        uint4 o;
        o.x = packbf((ax0 + w0.x) * sc, (ay0 + w0.y) * sc);
        o.y = packbf((ax1 + w0.z) * sc, (ay1 + w0.w) * sc);
        o.z = packbf((ax2 + w1.x) * sc, (ay2 + w1.y) * sc);
        o.w = packbf((ax3 + w1.z) * sc, (ay3 + w1.w) * sc);
        out4[(size_t)n0 * 16 + ql] = o;
    } else if (q == 1) {
        const float* p = accum + (size_t)n1 * 128 + ql * 8;
        f4 w0 = __builtin_nontemporal_load((const f4*)p);
        f4 w1 = __builtin_nontemporal_load((const f4*)(p + 4));
        float sc = scale[n1];
        uint4 o;
        o.x = packbf((bx0 + w0.x) * sc, (by0 + w0.y) * sc);
        o.y = packbf((bx1 + w0.z) * sc, (by1 + w0.w) * sc);
        o.z = packbf((bx2 + w1.x) * sc, (by2 + w1.y) * sc);
        o.w = packbf((bx3 + w1.z) * sc, (by3 + w1.w) * sc);
        out4[(size_t)n1 * 16 + ql] = o;
    }
}

// ---------------- per-feature sum/sumsq over padded bf16 h3 ----------------
#define CS_BLOCKS 625
#define CS_THREADS 256   // stride 160000 (mult of 64) -> fixed dword-slot per thread
__global__ __launch_bounds__(CS_THREADS) void col_stats_kernel(const uint* __restrict__ h,
                                                               float* __restrict__ colsum,
                                                               float* __restrict__ colsq) {
    int gtid = blockIdx.x * CS_THREADS + threadIdx.x;
    const int stride = CS_BLOCKS * CS_THREADS;
    const int total = N_NODES * ROW_PAD;
    float s0 = 0.f, s1 = 0.f, q0 = 0.f, q1 = 0.f;
    for (int i = gtid; i < total; i += stride) {   // pads are zero, harmless
        uint u = h[i];
        float a = bflo(u), b = bfhi(u);
        s0 += a; s1 += b; q0 += a * a; q1 += b * b;
    }
    __shared__ float ssum[IN_DIM], ssq[IN_DIM];
    if (threadIdx.x < IN_DIM) { ssum[threadIdx.x] = 0.f; ssq[threadIdx.x] = 0.f; }
    __syncthreads();
    int p = gtid & 63;
    if (p < ROW) {
        atomicAdd(&ssum[2 * p], s0);
        atomicAdd(&ssum[2 * p + 1], s1);
        atomicAdd(&ssq[2 * p], q0);
        atomicAdd(&ssq[2 * p + 1], q1);
    }
    __syncthreads();
    if (threadIdx.x < IN_DIM) {
        atomicAdd(&colsum[threadIdx.x], ssum[threadIdx.x]);
        atomicAdd(&colsq[threadIdx.x], ssq[threadIdx.x]);
    }
}

// ---------------- fold standardize into W,b ----------------
__global__ __launch_bounds__(256) void prep_kernel(const float* __restrict__ colsum,
                                                   const float* __restrict__ colsq,
                                                   const float* __restrict__ W,
                                                   const float* __restrict__ b,
                                                   float* __restrict__ Wt,
                                                   float* __restrict__ bp) {
    __shared__ float smean[IN_DIM];
    __shared__ float sinv[IN_DIM];
    int t = threadIdx.x;
    const float Nf = (float)N_NODES;
    if (t < IN_DIM) {
        float m = colsum[t] / Nf;
        float var = (colsq[t] - Nf * m * m) / (Nf - 1.0f);
        var = fmaxf(var, 1e-20f);
        smean[t] = m;
        sinv[t] = 1.0f / sqrtf(var);
    }
    __syncthreads();
    for (int i = t; i < IN_DIM * OUT_DIM; i += 256) {
        int o = i % OUT_DIM, f = i / OUT_DIM;
        Wt[f * OUT_DIM + o] = W[o * IN_DIM + f] * sinv[f];
    }
    if (t < OUT_DIM) {
        float acc = b[t];
        for (int f = 0; f < IN_DIM; ++f)
            acc -= smean[f] * W[t * IN_DIM + f] * sinv[f];
        bp[t] = acc;
    }
}

// ---------------- final linear: 10 threads/node, uint4 row reads, W' in LDS ----
__global__ __launch_bounds__(256) void final_kernel(const uint4* __restrict__ h4,
                                                    const float* __restrict__ Wt,
                                                    const float* __restrict__ bp,
                                                    float* __restrict__ out) {
    __shared__ float sW[104 * OUT_DIM];   // 16.25 KB
    __shared__ float sb[OUT_DIM];
    for (int i = threadIdx.x; i < 104 * OUT_DIM; i += 256)
        sW[i] = (i < IN_DIM * OUT_DIM) ? Wt[i] : 0.f;
    if (threadIdx.x < OUT_DIM) sb[threadIdx.x] = bp[threadIdx.x];
    __syncthreads();
    int t = blockIdx.x * 256 + threadIdx.x;
    if (t >= N_NODES * 10) return;
    int n = t / 10;
    int og = (t - n * 10) * 4;            // output group of 4
    const uint4* hr = h4 + (size_t)n * 16;
    float a0 = sb[og], a1 = sb[og + 1], a2 = sb[og + 2], a3 = sb[og + 3];
#pragma unroll
    for (int r = 0; r < 13; ++r) {        // dwords 0..51 (50,51 are zero pads)
        uint4 u = hr[r];
        int f = r * 8;
        float v0 = bflo(u.x), v1 = bfhi(u.x), v2 = bflo(u.y), v3 = bfhi(u.y);
        float v4 = bflo(u.z), v5 = bfhi(u.z), v6 = bflo(u.w), v7 = bfhi(u.w);
        const float* w0 = &sW[(f + 0) * OUT_DIM + og];
        const float* w1 = &sW[(f + 1) * OUT_DIM + og];
        const float* w2 = &sW[(f + 2) * OUT_DIM + og];
        const float* w3 = &sW[(f + 3) * OUT_DIM + og];
        const float* w4 = &sW[(f + 4) * OUT_DIM + og];
        const float* w5 = &sW[(f + 5) * OUT_DIM + og];
        const float* w6 = &sW[(f + 6) * OUT_DIM + og];
        const float* w7 = &sW[(f + 7) * OUT_DIM + og];
        a0 += v0 * w0[0] + v1 * w1[0] + v2 * w2[0] + v3 * w3[0]
            + v4 * w4[0] + v5 * w5[0] + v6 * w6[0] + v7 * w7[0];
        a1 += v0 * w0[1] + v1 * w1[1] + v2 * w2[1] + v3 * w3[1]
            + v4 * w4[1] + v5 * w5[1] + v6 * w6[1] + v7 * w7[1];
        a2 += v0 * w0[2] + v1 * w1[2] + v2 * w2[2] + v3 * w3[2]
            + v4 * w4[2] + v5 * w5[2] + v6 * w6[2] + v7 * w7[2];
        a3 += v0 * w0[3] + v1 * w1[3] + v2 * w2[3] + v3 * w3[3]
            + v4 * w4[3] + v5 * w5[3] + v6 * w6[3] + v7 * w7[3];
    }
    float4 o = make_float4(a0, a1, a2, a3);
    *((float4*)(out + (size_t)n * OUT_DIM + og)) = o;
}

extern "C" void kernel_launch(void* const* d_in, const int* in_sizes, int n_in,
                              void* d_out, int out_size, void* d_ws, size_t ws_size,
                              hipStream_t stream) {
    const float* feat = (const float*)d_in[0];   // [50000,100]
    const float* W    = (const float*)d_in[1];   // [40,100]
    const float* b    = (const float*)d_in[2];   // [40]
    const int*   src  = (const int*)d_in[3];     // [800000]
    const int*   dst  = (const int*)d_in[4];     // [800000]
    float* out = (float*)d_out;                  // [50000,40]

    char* w = (char*)d_ws;
    int*   deg2     = (int*)w;    w += 2 * N_NODES * 4;   // per-(node,shard) degree
    float* colsum   = (float*)w;  w += 128 * 4;
    float* colsq    = (float*)w;  w += 128 * 4;
    // ---- end of zero region: (2*N_NODES + 256) ints ----
    int*   eoff     = (int*)w;    w += N_EDGES * 4;
    int*   rowptr   = (int*)w;    w += 50004 * 4;
    float* norm     = (float*)w;  w += N_NODES * 4;
    float* norm2    = (float*)w;  w += N_NODES * 4;
    int*   blocksum = (int*)w;    w += 128 * 4;
    int*   blockoff = (int*)w;    w += 128 * 4;
    int*   csr      = (int*)w;    w += CSR_CAP * 4;
    float* Wt       = (float*)w;  w += IN_DIM * OUT_DIM * 4;
    float* bp       = (float*)w;  w += 64 * 4;
    // align row buffers to 256 B
    w = (char*)(((size_t)w + 255) & ~(size_t)255);
    const size_t HB = (size_t)(N_NODES + 1) * ROW_PAD * 4;   // padded rows + zero row
    uint*  fs       = (uint*)w;   w += HB;
    uint*  bufA     = (uint*)w;   w += HB;
    uint*  bufB     = (uint*)w;   w += HB;
    float* accum    = (float*)w;  w += (size_t)N_NODES * 128 * 4;   // f32 partial rows

    // 1. zero {deg2, colsum, colsq} + zero pad-rows
    {
        int nz = 2 * N_NODES + 256;
        zero_kernel<<<(nz + 255) / 256, 256, 0, stream>>>(deg2, nz, fs, bufA, bufB);
    }
    // 2. per-(dst,shard) in-degree + slot (single atomic per edge total)
    deg_kernel<<<(N_EDGES + 255) / 256, 256, 0, stream>>>(src, dst, deg2, eoff);
    // 3. rowptr over two 8-aligned segments + norm/norm2; scan3 fills pad slots
    scan1_kernel<<<NSCAN_BLK, SCAN_B, 0, stream>>>(deg2, rowptr, norm, norm2, blocksum);
    scan2_kernel<<<1, 128, 0, stream>>>(blocksum, blockoff, rowptr);
    scan3_kernel<<<NSCAN_BLK, SCAN_B, 0, stream>>>(rowptr, blockoff, deg2, csr);
    // 4. CSR scatter into shard segments (no atomics)
    csr_fill_kernel<<<(N_EDGES + 255) / 256, 256, 0, stream>>>(src, dst, rowptr, deg2, eoff, csr);
    // 5. pre-scale feat by norm into padded bf16 rows
    prescale_kernel<<<(N_NODES * 16 + 255) / 256, 256, 0, stream>>>(feat, norm, (uint4*)fs);
    // 6. three hops, each = shard-0 pass (f32 accum, NT) + shard-1 pass (finalize)
    {
        const int G = N_NODES / 4;   // 2 waves/block x 2 nodes/wave
        spmmA_kernel<<<G, 128, 0, stream>>>((const uint4*)fs, rowptr, deg2, csr, accum);
        spmmB_kernel<<<G, 128, 0, stream>>>((const uint4*)fs, rowptr, deg2, csr, accum, norm2, (uint4*)bufA);
        spmmA_kernel<<<G, 128, 0, stream>>>((const uint4*)bufA, rowptr, deg2, csr, accum);
        spmmB_kernel<<<G, 128, 0, stream>>>((const uint4*)bufA, rowptr, deg2, csr, accum, norm2, (uint4*)bufB);
        spmmA_kernel<<<G, 128, 0, stream>>>((const uint4*)bufB, rowptr, deg2, csr, accum);
        spmmB_kernel<<<G, 128, 0, stream>>>((const uint4*)bufB, rowptr, deg2, csr, accum, norm, (uint4*)bufA);
    }
    // 7. column stats on padded bf16 h3
    col_stats_kernel<<<CS_BLOCKS, CS_THREADS, 0, stream>>>(bufA, colsum, colsq);
    // 8. fold mean/std into W', b'
    prep_kernel<<<1, 256, 0, stream>>>(colsum, colsq, W, b, Wt, bp);
    // 9. final linear (10 threads per node)
    {
        int total = N_NODES * 10;
        final_kernel<<<(total + 255) / 256, 256, 0, stream>>>((const uint4*)bufA, Wt, bp, out);
    }
}

// Round 7
// 264.378 us; speedup vs baseline: 2.8066x; 1.2092x over previous
//
#include <hip/hip_runtime.h>

#define N_NODES 50000
#define N_EDGES 800000
#define IN_DIM 100
#define OUT_DIM 40
#define ROW 50            // 50 dwords = 100 bf16 per node row (used)
#define ROW_PAD 64        // padded pitch: 256 B -> one row = 16 lanes x dwordx4
#define SCAN_B 512
#define NSCAN_BLK ((N_NODES + SCAN_B - 1) / SCAN_B)   // 98
#define CSR_CAP (N_EDGES + N_NODES * 8 + 64)          // aligned-degree worst case

typedef unsigned int uint;

// ---- bf16 helpers (packed pair in one dword) ----
__device__ __forceinline__ float bflo(uint u) { return __uint_as_float(u << 16); }
__device__ __forceinline__ float bfhi(uint u) { return __uint_as_float(u & 0xffff0000u); }
__device__ __forceinline__ uint packbf(float a, float b) {
    uint ua = __float_as_uint(a), ub = __float_as_uint(b);
    ua = (ua + 0x7fffu + ((ua >> 16) & 1u)) >> 16;      // RNE
    ub = (ub + 0x7fffu + ((ub >> 16) & 1u)) >> 16;
    return ua | (ub << 16);
}

// ---------------- zero scratch: {deg, colsum, colsq} + 3 zero pad-rows ----------------
__global__ void zero_kernel(int* p, int n, uint* fs, uint* bufA, uint* bufB) {
    int i = blockIdx.x * blockDim.x + threadIdx.x;
    if (i < n) p[i] = 0;
    if (i < ROW_PAD) {   // full 256B pad row (index N_NODES)
        fs[(size_t)N_NODES * ROW_PAD + i] = 0u;
        bufA[(size_t)N_NODES * ROW_PAD + i] = 0u;
        bufB[(size_t)N_NODES * ROW_PAD + i] = 0u;
    }
}

// ---------------- in-degree; keep returned old count as the edge's slot ----------------
__global__ void deg_kernel(const int* __restrict__ dst, int* __restrict__ deg,
                           int* __restrict__ eoff) {
    int e = blockIdx.x * blockDim.x + threadIdx.x;
    if (e < N_EDGES) eoff[e] = atomicAdd(&deg[dst[e]], 1);
}

// ---------------- scan phase 1: scan ALIGNED degrees ((d+7)&~7), emit norms ----
__global__ __launch_bounds__(SCAN_B) void scan1_kernel(const int* __restrict__ deg,
                                                       int* __restrict__ rowptr,
                                                       float* __restrict__ norm,
                                                       float* __restrict__ norm2,
                                                       int* __restrict__ blocksum) {
    int i = blockIdx.x * SCAN_B + threadIdx.x;
    int lane = threadIdx.x & 63, wid = threadIdx.x >> 6;
    int d = (i < N_NODES) ? deg[i] : 0;
    int da = (d + 7) & ~7;          // pad each node's edge list to multiple of 8
    int v = da;
#pragma unroll
    for (int off = 1; off < 64; off <<= 1) {
        int t = __shfl_up(v, off);
        if (lane >= off) v += t;
    }
    __shared__ int wsum[8];
    if (lane == 63) wsum[wid] = v;
    __syncthreads();
    if (threadIdx.x < 8) {
        int w = wsum[threadIdx.x];
#pragma unroll
        for (int off = 1; off < 8; off <<= 1) {
            int t = __shfl_up(w, off);
            if (lane >= off) w += t;
        }
        wsum[threadIdx.x] = w;
    }
    __syncthreads();
    int woff = wid ? wsum[wid - 1] : 0;
    int incl = woff + v;
    if (i < N_NODES) {
        rowptr[i] = incl - da;
        float n1 = 1.0f / sqrtf((float)max(d, 1));
        norm[i] = n1;
        norm2[i] = n1 * n1;
    }
    if (threadIdx.x == SCAN_B - 1) blocksum[blockIdx.x] = incl;
}

// ---------------- scan phase 2 ----------------
__global__ __launch_bounds__(128) void scan2_kernel(const int* __restrict__ blocksum,
                                                    int* __restrict__ blockoff,
                                                    int* __restrict__ rowptr) {
    __shared__ int s[128];
    int t = threadIdx.x;
    int v = (t < NSCAN_BLK) ? blocksum[t] : 0;
    s[t] = v;
    __syncthreads();
    for (int off = 1; off < 128; off <<= 1) {
        int u = (t >= off) ? s[t - off] : 0;
        __syncthreads();
        s[t] += u;
        __syncthreads();
    }
    if (t < NSCAN_BLK) blockoff[t] = s[t] - v;
    if (t == 127) rowptr[N_NODES] = s[127];
}

// ---------------- scan phase 3: finalize rowptr + fill CSR pad slots ----------------
__global__ __launch_bounds__(SCAN_B) void scan3_kernel(int* __restrict__ rowptr,
                                                       const int* __restrict__ blockoff,
                                                       const int* __restrict__ deg,
                                                       int* __restrict__ csr) {
    int i = blockIdx.x * SCAN_B + threadIdx.x;
    if (i < N_NODES) {
        int rp = rowptr[i] + blockoff[blockIdx.x];
        rowptr[i] = rp;
        int d = deg[i], da = (d + 7) & ~7;
        for (int k = d; k < da; ++k) csr[rp + k] = N_NODES;   // dummy -> zero row
    }
}

// ---------------- CSR scatter, atomic-free (slot precomputed in eoff) ----------------
__global__ void csr_fill_kernel(const int* __restrict__ src, const int* __restrict__ dst,
                                const int* __restrict__ rowptr,
                                const int* __restrict__ eoff,
                                int* __restrict__ csr) {
    int e = blockIdx.x * blockDim.x + threadIdx.x;
    if (e < N_EDGES) csr[rowptr[dst[e]] + eoff[e]] = src[e];
}

// ---------------- pre-scale: fs = bf16(norm ⊙ feat), full padded rows, uint4 ----
__global__ __launch_bounds__(256) void prescale_kernel(const float* __restrict__ feat,
                                                       const float* __restrict__ norm,
                                                       uint4* __restrict__ fs4) {
    int t = blockIdx.x * 256 + threadIdx.x;   // N_NODES*16 threads
    if (t >= N_NODES * 16) return;
    int n = t >> 4, ql = t & 15;
    float nm = norm[n];
    uint4 o = make_uint4(0u, 0u, 0u, 0u);
    const float4* fr = (const float4*)(feat + (size_t)n * IN_DIM);
    if (ql < 12) {
        float4 a = fr[2 * ql], b2 = fr[2 * ql + 1];
        o.x = packbf(a.x * nm, a.y * nm);  o.y = packbf(a.z * nm, a.w * nm);
        o.z = packbf(b2.x * nm, b2.y * nm); o.w = packbf(b2.z * nm, b2.w * nm);
    } else if (ql == 12) {
        float4 a = fr[24];                 // features 96..99
        o.x = packbf(a.x * nm, a.y * nm);  o.y = packbf(a.z * nm, a.w * nm);
    }
    fs4[t] = o;
}

// ---------------- SGC hop: QUARTER-PER-NODE ----------------
// Each 16-lane quarter owns one node: its lanes hold the node's full 256B row
// slice in registers and walk the quarter's own 8-aligned edge list.
//  - src indices: two broadcast int4 loads per 8 edges (csr is 8-aligned) ->
//    0.31 VMEM instructions/edge.
//  - 8 independent row-gathers per iteration -> 8 gathers in flight per wave
//    (2x round-2's 4), doubling per-CU outstanding requests at equal waves/CU.
//  - no cross-quarter shuffle reduce; all 64 lanes store -> wave writes its 4
//    consecutive nodes as one contiguous 1KB store.
//  - quarters with shorter lists are exec-masked (no dummy requests).
// Numerics identical to round 2: bf16 in, f32 accumulate, bf16 out.
__global__ __launch_bounds__(128) void spmm_kernel(const uint4* __restrict__ H4,
                                                   const int* __restrict__ rowptr,
                                                   const int* __restrict__ csr,
                                                   const float* __restrict__ scale,
                                                   uint4* __restrict__ out4) {
    const int l = threadIdx.x & 63;
    const int q = l >> 4;                 // quarter 0..3 -> node within wave
    const int ql = l & 15;                // lane within quarter = 16B slice
    const int n = blockIdx.x * 8 + (threadIdx.x >> 6) * 4 + q;
    int j = rowptr[n];
    const int e = rowptr[n + 1];          // span is a multiple of 8, 8-aligned base
    float ax0 = 0.f, ay0 = 0.f, ax1 = 0.f, ay1 = 0.f;
    float ax2 = 0.f, ay2 = 0.f, ax3 = 0.f, ay3 = 0.f;
    while (j < e) {
        const int4* cp = (const int4*)(csr + j);   // 32B-aligned (j % 8 == 0)
        int4 sa = cp[0];
        int4 sb = cp[1];
        uint4 u0 = H4[(size_t)sa.x * 16 + ql];
        uint4 u1 = H4[(size_t)sa.y * 16 + ql];
        uint4 u2 = H4[(size_t)sa.z * 16 + ql];
        uint4 u3 = H4[(size_t)sa.w * 16 + ql];
        uint4 u4 = H4[(size_t)sb.x * 16 + ql];
        uint4 u5 = H4[(size_t)sb.y * 16 + ql];
        uint4 u6 = H4[(size_t)sb.z * 16 + ql];
        uint4 u7 = H4[(size_t)sb.w * 16 + ql];
        ax0 += bflo(u0.x); ay0 += bfhi(u0.x);
        ax1 += bflo(u0.y); ay1 += bfhi(u0.y);
        ax2 += bflo(u0.z); ay2 += bfhi(u0.z);
        ax3 += bflo(u0.w); ay3 += bfhi(u0.w);
        ax0 += bflo(u1.x); ay0 += bfhi(u1.x);
        ax1 += bflo(u1.y); ay1 += bfhi(u1.y);
        ax2 += bflo(u1.z); ay2 += bfhi(u1.z);
        ax3 += bflo(u1.w); ay3 += bfhi(u1.w);
        ax0 += bflo(u2.x); ay0 += bfhi(u2.x);
        ax1 += bflo(u2.y); ay1 += bfhi(u2.y);
        ax2 += bflo(u2.z); ay2 += bfhi(u2.z);
        ax3 += bflo(u2.w); ay3 += bfhi(u2.w);
        ax0 += bflo(u3.x); ay0 += bfhi(u3.x);
        ax1 += bflo(u3.y); ay1 += bfhi(u3.y);
        ax2 += bflo(u3.z); ay2 += bfhi(u3.z);
        ax3 += bflo(u3.w); ay3 += bfhi(u3.w);
        ax0 += bflo(u4.x); ay0 += bfhi(u4.x);
        ax1 += bflo(u4.y); ay1 += bfhi(u4.y);
        ax2 += bflo(u4.z); ay2 += bfhi(u4.z);
        ax3 += bflo(u4.w); ay3 += bfhi(u4.w);
        ax0 += bflo(u5.x); ay0 += bfhi(u5.x);
        ax1 += bflo(u5.y); ay1 += bfhi(u5.y);
        ax2 += bflo(u5.z); ay2 += bfhi(u5.z);
        ax3 += bflo(u5.w); ay3 += bfhi(u5.w);
        ax0 += bflo(u6.x); ay0 += bfhi(u6.x);
        ax1 += bflo(u6.y); ay1 += bfhi(u6.y);
        ax2 += bflo(u6.z); ay2 += bfhi(u6.z);
        ax3 += bflo(u6.w); ay3 += bfhi(u6.w);
        ax0 += bflo(u7.x); ay0 += bfhi(u7.x);
        ax1 += bflo(u7.y); ay1 += bfhi(u7.y);
        ax2 += bflo(u7.z); ay2 += bfhi(u7.z);
        ax3 += bflo(u7.w); ay3 += bfhi(u7.w);
        j += 8;
    }
    float sc = scale[n];
    uint4 o;
    o.x = packbf(ax0 * sc, ay0 * sc);
    o.y = packbf(ax1 * sc, ay1 * sc);
    o.z = packbf(ax2 * sc, ay2 * sc);
    o.w = packbf(ax3 * sc, ay3 * sc);
    out4[(size_t)n * 16 + ql] = o;        // wave stores 4 consecutive rows = 1KB
}

// ---------------- per-feature sum/sumsq over padded bf16 h3 ----------------
#define CS_BLOCKS 625
#define CS_THREADS 256   // stride 160000 (mult of 64) -> fixed dword-slot per thread
__global__ __launch_bounds__(CS_THREADS) void col_stats_kernel(const uint* __restrict__ h,
                                                               float* __restrict__ colsum,
                                                               float* __restrict__ colsq) {
    int gtid = blockIdx.x * CS_THREADS + threadIdx.x;
    const int stride = CS_BLOCKS * CS_THREADS;
    const int total = N_NODES * ROW_PAD;
    float s0 = 0.f, s1 = 0.f, q0 = 0.f, q1 = 0.f;
    for (int i = gtid; i < total; i += stride) {   // pads are zero, harmless
        uint u = h[i];
        float a = bflo(u), b = bfhi(u);
        s0 += a; s1 += b; q0 += a * a; q1 += b * b;
    }
    __shared__ float ssum[IN_DIM], ssq[IN_DIM];
    if (threadIdx.x < IN_DIM) { ssum[threadIdx.x] = 0.f; ssq[threadIdx.x] = 0.f; }
    __syncthreads();
    int p = gtid & 63;
    if (p < ROW) {
        atomicAdd(&ssum[2 * p], s0);
        atomicAdd(&ssum[2 * p + 1], s1);
        atomicAdd(&ssq[2 * p], q0);
        atomicAdd(&ssq[2 * p + 1], q1);
    }
    __syncthreads();
    if (threadIdx.x < IN_DIM) {
        atomicAdd(&colsum[threadIdx.x], ssum[threadIdx.x]);
        atomicAdd(&colsq[threadIdx.x], ssq[threadIdx.x]);
    }
}

// ---------------- fold standardize into W,b ----------------
__global__ __launch_bounds__(256) void prep_kernel(const float* __restrict__ colsum,
                                                   const float* __restrict__ colsq,
                                                   const float* __restrict__ W,
                                                   const float* __restrict__ b,
                                                   float* __restrict__ Wt,
                                                   float* __restrict__ bp) {
    __shared__ float smean[IN_DIM];
    __shared__ float sinv[IN_DIM];
    int t = threadIdx.x;
    const float Nf = (float)N_NODES;
    if (t < IN_DIM) {
        float m = colsum[t] / Nf;
        float var = (colsq[t] - Nf * m * m) / (Nf - 1.0f);
        var = fmaxf(var, 1e-20f);
        smean[t] = m;
        sinv[t] = 1.0f / sqrtf(var);
    }
    __syncthreads();
    for (int i = t; i < IN_DIM * OUT_DIM; i += 256) {
        int o = i % OUT_DIM, f = i / OUT_DIM;
        Wt[f * OUT_DIM + o] = W[o * IN_DIM + f] * sinv[f];
    }
    if (t < OUT_DIM) {
        float acc = b[t];
        for (int f = 0; f < IN_DIM; ++f)
            acc -= smean[f] * W[t * IN_DIM + f] * sinv[f];
        bp[t] = acc;
    }
}

// ---------------- final linear: 10 threads/node, uint4 row reads, W' in LDS ----
// sW padded to 104 features (rows 100..103 = 0) so the 13th uint4 (dwords
// 48..51, features 96..103) needs no special-casing.
__global__ __launch_bounds__(256) void final_kernel(const uint4* __restrict__ h4,
                                                    const float* __restrict__ Wt,
                                                    const float* __restrict__ bp,
                                                    float* __restrict__ out) {
    __shared__ float sW[104 * OUT_DIM];   // 16.25 KB
    __shared__ float sb[OUT_DIM];
    for (int i = threadIdx.x; i < 104 * OUT_DIM; i += 256)
        sW[i] = (i < IN_DIM * OUT_DIM) ? Wt[i] : 0.f;
    if (threadIdx.x < OUT_DIM) sb[threadIdx.x] = bp[threadIdx.x];
    __syncthreads();
    int t = blockIdx.x * 256 + threadIdx.x;
    if (t >= N_NODES * 10) return;
    int n = t / 10;
    int og = (t - n * 10) * 4;            // output group of 4
    const uint4* hr = h4 + (size_t)n * 16;
    float a0 = sb[og], a1 = sb[og + 1], a2 = sb[og + 2], a3 = sb[og + 3];
#pragma unroll
    for (int r = 0; r < 13; ++r) {        // dwords 0..51 (50,51 are zero pads)
        uint4 u = hr[r];
        int f = r * 8;
        float v0 = bflo(u.x), v1 = bfhi(u.x), v2 = bflo(u.y), v3 = bfhi(u.y);
        float v4 = bflo(u.z), v5 = bfhi(u.z), v6 = bflo(u.w), v7 = bfhi(u.w);
        const float* w0 = &sW[(f + 0) * OUT_DIM + og];
        const float* w1 = &sW[(f + 1) * OUT_DIM + og];
        const float* w2 = &sW[(f + 2) * OUT_DIM + og];
        const float* w3 = &sW[(f + 3) * OUT_DIM + og];
        const float* w4 = &sW[(f + 4) * OUT_DIM + og];
        const float* w5 = &sW[(f + 5) * OUT_DIM + og];
        const float* w6 = &sW[(f + 6) * OUT_DIM + og];
        const float* w7 = &sW[(f + 7) * OUT_DIM + og];
        a0 += v0 * w0[0] + v1 * w1[0] + v2 * w2[0] + v3 * w3[0]
            + v4 * w4[0] + v5 * w5[0] + v6 * w6[0] + v7 * w7[0];
        a1 += v0 * w0[1] + v1 * w1[1] + v2 * w2[1] + v3 * w3[1]
            + v4 * w4[1] + v5 * w5[1] + v6 * w6[1] + v7 * w7[1];
        a2 += v0 * w0[2] + v1 * w1[2] + v2 * w2[2] + v3 * w3[2]
            + v4 * w4[2] + v5 * w5[2] + v6 * w6[2] + v7 * w7[2];
        a3 += v0 * w0[3] + v1 * w1[3] + v2 * w2[3] + v3 * w3[3]
            + v4 * w4[3] + v5 * w5[3] + v6 * w6[3] + v7 * w7[3];
    }
    float4 o = make_float4(a0, a1, a2, a3);
    *((float4*)(out + (size_t)n * OUT_DIM + og)) = o;
}

extern "C" void kernel_launch(void* const* d_in, const int* in_sizes, int n_in,
                              void* d_out, int out_size, void* d_ws, size_t ws_size,
                              hipStream_t stream) {
    const float* feat = (const float*)d_in[0];   // [50000,100]
    const float* W    = (const float*)d_in[1];   // [40,100]
    const float* b    = (const float*)d_in[2];   // [40]
    const int*   src  = (const int*)d_in[3];     // [800000]
    const int*   dst  = (const int*)d_in[4];     // [800000]
    float* out = (float*)d_out;                  // [50000,40]

    char* w = (char*)d_ws;
    int*   deg      = (int*)w;    w += N_NODES * 4;
    float* colsum   = (float*)w;  w += 128 * 4;
    float* colsq    = (float*)w;  w += 128 * 4;
    // ---- end of zero region: (N_NODES + 256) ints ----
    int*   eoff     = (int*)w;    w += N_EDGES * 4;
    int*   rowptr   = (int*)w;    w += 50004 * 4;
    float* norm     = (float*)w;  w += N_NODES * 4;
    float* norm2    = (float*)w;  w += N_NODES * 4;
    int*   blocksum = (int*)w;    w += 128 * 4;
    int*   blockoff = (int*)w;    w += 128 * 4;
    int*   csr      = (int*)w;    w += CSR_CAP * 4;
    float* Wt       = (float*)w;  w += IN_DIM * OUT_DIM * 4;
    float* bp       = (float*)w;  w += 64 * 4;
    // align row buffers to 256 B
    w = (char*)(((size_t)w + 255) & ~(size_t)255);
    const size_t HB = (size_t)(N_NODES + 1) * ROW_PAD * 4;   // padded rows + zero row
    uint*  fs       = (uint*)w;   w += HB;
    uint*  bufA     = (uint*)w;   w += HB;
    uint*  bufB     = (uint*)w;   w += HB;

    // 1. zero {deg, colsum, colsq} + zero pad-rows
    {
        int nz = N_NODES + 256;
        zero_kernel<<<(nz + 255) / 256, 256, 0, stream>>>(deg, nz, fs, bufA, bufB);
    }
    // 2. in-degree + per-edge slot (single atomic per edge total)
    deg_kernel<<<(N_EDGES + 255) / 256, 256, 0, stream>>>(dst, deg, eoff);
    // 3. rowptr over 8-aligned degrees + norm/norm2; scan3 also fills CSR pad slots
    scan1_kernel<<<NSCAN_BLK, SCAN_B, 0, stream>>>(deg, rowptr, norm, norm2, blocksum);
    scan2_kernel<<<1, 128, 0, stream>>>(blocksum, blockoff, rowptr);
    scan3_kernel<<<NSCAN_BLK, SCAN_B, 0, stream>>>(rowptr, blockoff, deg, csr);
    // 4. CSR scatter (no atomics)
    csr_fill_kernel<<<(N_EDGES + 255) / 256, 256, 0, stream>>>(src, dst, rowptr, eoff, csr);
    // 5. pre-scale feat by norm into padded bf16 rows
    prescale_kernel<<<(N_NODES * 16 + 255) / 256, 256, 0, stream>>>(feat, norm, (uint4*)fs);
    // 6. three hops: g1 = norm2*S(fs); g2 = norm2*S(g1); h3 = norm*S(g2)
    //    quarter-per-node: 8 nodes per 128-thread block
    spmm_kernel<<<N_NODES / 8, 128, 0, stream>>>((const uint4*)fs, rowptr, csr, norm2, (uint4*)bufA);
    spmm_kernel<<<N_NODES / 8, 128, 0, stream>>>((const uint4*)bufA, rowptr, csr, norm2, (uint4*)bufB);
    spmm_kernel<<<N_NODES / 8, 128, 0, stream>>>((const uint4*)bufB, rowptr, csr, norm, (uint4*)bufA);
    // 7. column stats on padded bf16 h3
    col_stats_kernel<<<CS_BLOCKS, CS_THREADS, 0, stream>>>(bufA, colsum, colsq);
    // 8. fold mean/std into W', b'
    prep_kernel<<<1, 256, 0, stream>>>(colsum, colsq, W, b, Wt, bp);
    // 9. final linear (10 threads per node)
    {
        int total = N_NODES * 10;
        final_kernel<<<(total + 255) / 256, 256, 0, stream>>>((const uint4*)bufA, Wt, bp, out);
    }
}

// Round 8
// 258.289 us; speedup vs baseline: 2.8728x; 1.0236x over previous
//
#include <hip/hip_runtime.h>

#define N_NODES 50000
#define N_EDGES 800000
#define IN_DIM 100
#define OUT_DIM 40
#define ROW 50            // 50 dwords = 100 bf16 per node row (used)
#define ROW_PAD 64        // padded pitch: 256 B -> one row = 16 lanes x dwordx4
#define SCAN_B 512
#define NSCAN_BLK ((N_NODES + SCAN_B - 1) / SCAN_B)   // 98
#define CSR_CAP (N_EDGES + N_NODES * 8 + 64)          // aligned-degree worst case
#define CSRF_BLOCKS ((N_EDGES + 255) / 256)           // 3125
#define PRE_BLOCKS ((N_NODES * 16 + 255) / 256)       // 3125

typedef unsigned int uint;

// ---- bf16 helpers (packed pair in one dword) ----
__device__ __forceinline__ float bflo(uint u) { return __uint_as_float(u << 16); }
__device__ __forceinline__ float bfhi(uint u) { return __uint_as_float(u & 0xffff0000u); }
__device__ __forceinline__ uint packbf(float a, float b) {
    uint ua = __float_as_uint(a), ub = __float_as_uint(b);
    ua = (ua + 0x7fffu + ((ua >> 16) & 1u)) >> 16;      // RNE
    ub = (ub + 0x7fffu + ((ub >> 16) & 1u)) >> 16;
    return ua | (ub << 16);
}

// ---------------- zero scratch: {deg, colsum, colsq} + 3 zero pad-rows ----------------
__global__ void zero_kernel(int* p, int n, uint* fs, uint* bufA, uint* bufB) {
    int i = blockIdx.x * blockDim.x + threadIdx.x;
    if (i < n) p[i] = 0;
    if (i < ROW_PAD) {   // full 256B pad row (index N_NODES)
        fs[(size_t)N_NODES * ROW_PAD + i] = 0u;
        bufA[(size_t)N_NODES * ROW_PAD + i] = 0u;
        bufB[(size_t)N_NODES * ROW_PAD + i] = 0u;
    }
}

// ---------------- in-degree; keep returned old count as the edge's slot ----------------
__global__ void deg_kernel(const int* __restrict__ dst, int* __restrict__ deg,
                           int* __restrict__ eoff) {
    int e = blockIdx.x * blockDim.x + threadIdx.x;
    if (e < N_EDGES) eoff[e] = atomicAdd(&deg[dst[e]], 1);
}

// ---------------- scan phase 1: scan ALIGNED degrees ((d+7)&~7), emit norms ----
__global__ __launch_bounds__(SCAN_B) void scan1_kernel(const int* __restrict__ deg,
                                                       int* __restrict__ rowptr,
                                                       float* __restrict__ norm,
                                                       float* __restrict__ norm2,
                                                       int* __restrict__ blocksum) {
    int i = blockIdx.x * SCAN_B + threadIdx.x;
    int lane = threadIdx.x & 63, wid = threadIdx.x >> 6;
    int d = (i < N_NODES) ? deg[i] : 0;
    int da = (d + 7) & ~7;          // pad each node's edge list to multiple of 8
    int v = da;
#pragma unroll
    for (int off = 1; off < 64; off <<= 1) {
        int t = __shfl_up(v, off);
        if (lane >= off) v += t;
    }
    __shared__ int wsum[8];
    if (lane == 63) wsum[wid] = v;
    __syncthreads();
    if (threadIdx.x < 8) {
        int w = wsum[threadIdx.x];
#pragma unroll
        for (int off = 1; off < 8; off <<= 1) {
            int t = __shfl_up(w, off);
            if (lane >= off) w += t;
        }
        wsum[threadIdx.x] = w;
    }
    __syncthreads();
    int woff = wid ? wsum[wid - 1] : 0;
    int incl = woff + v;
    if (i < N_NODES) {
        rowptr[i] = incl - da;      // block-local exclusive prefix
        float n1 = 1.0f / sqrtf((float)max(d, 1));
        norm[i] = n1;
        norm2[i] = n1 * n1;
    }
    if (threadIdx.x == SCAN_B - 1) blocksum[blockIdx.x] = incl;
}

// ---- scan phase 2+3 merged: each block reduces its own offset over blocksum ----
// (98 entries; wave-0 sums the <b prefix via two guarded reads + shfl reduce,
//  ~9.6K redundant L2-cached reads total -- removes the serialized single-block
//  scan2 launch). Also finalizes rowptr and fills CSR pad slots.
__global__ __launch_bounds__(SCAN_B) void scan3_kernel(int* __restrict__ rowptr,
                                                       const int* __restrict__ blocksum,
                                                       const int* __restrict__ deg,
                                                       int* __restrict__ csr) {
    __shared__ int s_off;
    const int b = blockIdx.x;
    if (threadIdx.x < 64) {
        int lane = threadIdx.x;
        int v = (lane < b) ? blocksum[lane] : 0;
        if (lane + 64 < b) v += blocksum[lane + 64];
#pragma unroll
        for (int off = 32; off >= 1; off >>= 1) v += __shfl_xor(v, off);
        if (lane == 0) s_off = v;
    }
    __syncthreads();
    const int boff = s_off;
    int i = b * SCAN_B + threadIdx.x;
    if (i < N_NODES) {
        int rp = rowptr[i] + boff;
        rowptr[i] = rp;
        int d = deg[i], da = (d + 7) & ~7;
        for (int k = d; k < da; ++k) csr[rp + k] = N_NODES;   // dummy -> zero row
    }
    if (b == NSCAN_BLK - 1 && threadIdx.x == 0)
        rowptr[N_NODES] = boff + blocksum[b];
}

// ------- merged: CSR scatter (blocks 0..3124) || prescale (blocks 3125..6249) -------
// Both depend only on scan3 (rowptr) / scan1 (norm) respectively; merging the two
// independent kernels into one launch overlaps their execution on one stream.
__global__ __launch_bounds__(256) void fill_prescale_kernel(const int* __restrict__ src,
                                                            const int* __restrict__ dst,
                                                            const int* __restrict__ rowptr,
                                                            const int* __restrict__ eoff,
                                                            int* __restrict__ csr,
                                                            const float* __restrict__ feat,
                                                            const float* __restrict__ norm,
                                                            uint4* __restrict__ fs4) {
    if (blockIdx.x < CSRF_BLOCKS) {
        int e = blockIdx.x * 256 + threadIdx.x;
        if (e < N_EDGES) csr[rowptr[dst[e]] + eoff[e]] = src[e];
    } else {
        int t = (blockIdx.x - CSRF_BLOCKS) * 256 + threadIdx.x;   // N_NODES*16 threads
        if (t >= N_NODES * 16) return;
        int n = t >> 4, ql = t & 15;
        float nm = norm[n];
        uint4 o = make_uint4(0u, 0u, 0u, 0u);
        const float4* fr = (const float4*)(feat + (size_t)n * IN_DIM);
        if (ql < 12) {
            float4 a = fr[2 * ql], b2 = fr[2 * ql + 1];
            o.x = packbf(a.x * nm, a.y * nm);  o.y = packbf(a.z * nm, a.w * nm);
            o.z = packbf(b2.x * nm, b2.y * nm); o.w = packbf(b2.z * nm, b2.w * nm);
        } else if (ql == 12) {
            float4 a = fr[24];                 // features 96..99
            o.x = packbf(a.x * nm, a.y * nm);  o.y = packbf(a.z * nm, a.w * nm);
        }
        fs4[t] = o;
    }
}

// ---------------- SGC hop: out[n] = bf16( scale[n] * sum_{s in N(n)} H[s] ) ----
// Verified-best form (round-2, 261.9us): one wave per node, quarter-wave gather,
// 16 edges/iter with 4 csr loads + 4 row gathers in flight, 8-edge tail.
// The spmm plateau is a line-rate wall (~23G random 128B-line requests/s,
// invariant under depth 1/2/4/8 and two locality restructurings); 2 lines/edge
// is the minimum for a 200B row, so this loop is at its structural floor.
__global__ __launch_bounds__(128) void spmm_kernel(const uint4* __restrict__ H4,
                                                   const int* __restrict__ rowptr,
                                                   const int* __restrict__ csr,
                                                   const float* __restrict__ scale,
                                                   uint4* __restrict__ out4) {
    const int n = blockIdx.x * 2 + (threadIdx.x >> 6);
    const int l = threadIdx.x & 63;
    const int q = l >> 4;          // quarter 0..3
    const int ql = l & 15;         // lane within quarter
    const int beg = rowptr[n], end = rowptr[n + 1];   // multiple-of-8 span
    float ax0 = 0.f, ax1 = 0.f, ax2 = 0.f, ax3 = 0.f;
    float ay0 = 0.f, ay1 = 0.f, ay2 = 0.f, ay3 = 0.f;
    int j = beg;
    for (; j + 16 <= end; j += 16) {
        int s0 = csr[j + q];
        int s1 = csr[j + 4 + q];
        int s2 = csr[j + 8 + q];
        int s3 = csr[j + 12 + q];
        uint4 u0 = H4[(size_t)s0 * 16 + ql];
        uint4 u1 = H4[(size_t)s1 * 16 + ql];
        uint4 u2 = H4[(size_t)s2 * 16 + ql];
        uint4 u3 = H4[(size_t)s3 * 16 + ql];
        ax0 += bflo(u0.x); ay0 += bfhi(u0.x);
        ax1 += bflo(u0.y); ay1 += bfhi(u0.y);
        ax2 += bflo(u0.z); ay2 += bfhi(u0.z);
        ax3 += bflo(u0.w); ay3 += bfhi(u0.w);
        ax0 += bflo(u1.x); ay0 += bfhi(u1.x);
        ax1 += bflo(u1.y); ay1 += bfhi(u1.y);
        ax2 += bflo(u1.z); ay2 += bfhi(u1.z);
        ax3 += bflo(u1.w); ay3 += bfhi(u1.w);
        ax0 += bflo(u2.x); ay0 += bfhi(u2.x);
        ax1 += bflo(u2.y); ay1 += bfhi(u2.y);
        ax2 += bflo(u2.z); ay2 += bfhi(u2.z);
        ax3 += bflo(u2.w); ay3 += bfhi(u2.w);
        ax0 += bflo(u3.x); ay0 += bfhi(u3.x);
        ax1 += bflo(u3.y); ay1 += bfhi(u3.y);
        ax2 += bflo(u3.z); ay2 += bfhi(u3.z);
        ax3 += bflo(u3.w); ay3 += bfhi(u3.w);
    }
    if (j < end) {                 // 8-edge tail
        int s0 = csr[j + q];
        int s1 = csr[j + 4 + q];
        uint4 u0 = H4[(size_t)s0 * 16 + ql];
        uint4 u1 = H4[(size_t)s1 * 16 + ql];
        ax0 += bflo(u0.x); ay0 += bfhi(u0.x);
        ax1 += bflo(u0.y); ay1 += bfhi(u0.y);
        ax2 += bflo(u0.z); ay2 += bfhi(u0.z);
        ax3 += bflo(u0.w); ay3 += bfhi(u0.w);
        ax0 += bflo(u1.x); ay0 += bfhi(u1.x);
        ax1 += bflo(u1.y); ay1 += bfhi(u1.y);
        ax2 += bflo(u1.z); ay2 += bfhi(u1.z);
        ax3 += bflo(u1.w); ay3 += bfhi(u1.w);
    }
    // reduce the 4 quarters (lanes l ^ 16 ^ 32)
    ax0 += __shfl_xor(ax0, 16); ax1 += __shfl_xor(ax1, 16);
    ax2 += __shfl_xor(ax2, 16); ax3 += __shfl_xor(ax3, 16);
    ay0 += __shfl_xor(ay0, 16); ay1 += __shfl_xor(ay1, 16);
    ay2 += __shfl_xor(ay2, 16); ay3 += __shfl_xor(ay3, 16);
    ax0 += __shfl_xor(ax0, 32); ax1 += __shfl_xor(ax1, 32);
    ax2 += __shfl_xor(ax2, 32); ax3 += __shfl_xor(ax3, 32);
    ay0 += __shfl_xor(ay0, 32); ay1 += __shfl_xor(ay1, 32);
    ay2 += __shfl_xor(ay2, 32); ay3 += __shfl_xor(ay3, 32);
    if (q == 0) {
        float sc = scale[n];
        uint4 o;
        o.x = packbf(ax0 * sc, ay0 * sc);
        o.y = packbf(ax1 * sc, ay1 * sc);
        o.z = packbf(ax2 * sc, ay2 * sc);
        o.w = packbf(ax3 * sc, ay3 * sc);
        out4[(size_t)n * 16 + ql] = o;   // full row incl. zero pads
    }
}

// ---------------- per-feature sum/sumsq over padded bf16 h3 ----------------
#define CS_BLOCKS 625
#define CS_THREADS 256   // stride 160000 (mult of 64) -> fixed dword-slot per thread
__global__ __launch_bounds__(CS_THREADS) void col_stats_kernel(const uint* __restrict__ h,
                                                               float* __restrict__ colsum,
                                                               float* __restrict__ colsq) {
    int gtid = blockIdx.x * CS_THREADS + threadIdx.x;
    const int stride = CS_BLOCKS * CS_THREADS;
    const int total = N_NODES * ROW_PAD;
    float s0 = 0.f, s1 = 0.f, q0 = 0.f, q1 = 0.f;
    for (int i = gtid; i < total; i += stride) {   // pads are zero, harmless
        uint u = h[i];
        float a = bflo(u), b = bfhi(u);
        s0 += a; s1 += b; q0 += a * a; q1 += b * b;
    }
    __shared__ float ssum[IN_DIM], ssq[IN_DIM];
    if (threadIdx.x < IN_DIM) { ssum[threadIdx.x] = 0.f; ssq[threadIdx.x] = 0.f; }
    __syncthreads();
    int p = gtid & 63;
    if (p < ROW) {
        atomicAdd(&ssum[2 * p], s0);
        atomicAdd(&ssum[2 * p + 1], s1);
        atomicAdd(&ssq[2 * p], q0);
        atomicAdd(&ssq[2 * p + 1], q1);
    }
    __syncthreads();
    if (threadIdx.x < IN_DIM) {
        atomicAdd(&colsum[threadIdx.x], ssum[threadIdx.x]);
        atomicAdd(&colsq[threadIdx.x], ssq[threadIdx.x]);
    }
}

// ------- final linear with fused standardize-fold (prep merged into each block) -------
// Each block derives smean/sinv from colsum/colsq (L2-cached, 800B), builds
// sW = W*sinv and sb = b - smean . sW in LDS, then does the 10-threads/node GEMV.
// Removes the prep launch and the Wt/bp global round-trip; f32 op order preserved.
__global__ __launch_bounds__(256) void final_kernel(const uint4* __restrict__ h4,
                                                    const float* __restrict__ colsum,
                                                    const float* __restrict__ colsq,
                                                    const float* __restrict__ W,
                                                    const float* __restrict__ bvec,
                                                    float* __restrict__ out) {
    __shared__ float sW[104 * OUT_DIM];   // 16.25 KB (rows 100..103 = 0)
    __shared__ float sb[OUT_DIM];
    __shared__ float smean[IN_DIM];
    __shared__ float sinv[IN_DIM];
    const int tid = threadIdx.x;
    const float Nf = (float)N_NODES;
    if (tid < IN_DIM) {
        float m = colsum[tid] / Nf;
        float var = (colsq[tid] - Nf * m * m) / (Nf - 1.0f);
        var = fmaxf(var, 1e-20f);
        smean[tid] = m;
        sinv[tid] = 1.0f / sqrtf(var);
    }
    __syncthreads();
    for (int i = tid; i < 104 * OUT_DIM; i += 256) {
        int f = i / OUT_DIM, o = i % OUT_DIM;
        sW[i] = (f < IN_DIM) ? W[o * IN_DIM + f] * sinv[f] : 0.f;
    }
    __syncthreads();
    if (tid < OUT_DIM) {
        float acc = bvec[tid];
        for (int f = 0; f < IN_DIM; ++f)
            acc -= smean[f] * sW[f * OUT_DIM + tid];
        sb[tid] = acc;
    }
    __syncthreads();
    int t = blockIdx.x * 256 + tid;
    if (t >= N_NODES * 10) return;
    int n = t / 10;
    int og = (t - n * 10) * 4;            // output group of 4
    const uint4* hr = h4 + (size_t)n * 16;
    float a0 = sb[og], a1 = sb[og + 1], a2 = sb[og + 2], a3 = sb[og + 3];
#pragma unroll
    for (int r = 0; r < 13; ++r) {        // dwords 0..51 (50,51 are zero pads)
        uint4 u = hr[r];
        int f = r * 8;
        float v0 = bflo(u.x), v1 = bfhi(u.x), v2 = bflo(u.y), v3 = bfhi(u.y);
        float v4 = bflo(u.z), v5 = bfhi(u.z), v6 = bflo(u.w), v7 = bfhi(u.w);
        const float* w0 = &sW[(f + 0) * OUT_DIM + og];
        const float* w1 = &sW[(f + 1) * OUT_DIM + og];
        const float* w2 = &sW[(f + 2) * OUT_DIM + og];
        const float* w3 = &sW[(f + 3) * OUT_DIM + og];
        const float* w4 = &sW[(f + 4) * OUT_DIM + og];
        const float* w5 = &sW[(f + 5) * OUT_DIM + og];
        const float* w6 = &sW[(f + 6) * OUT_DIM + og];
        const float* w7 = &sW[(f + 7) * OUT_DIM + og];
        a0 += v0 * w0[0] + v1 * w1[0] + v2 * w2[0] + v3 * w3[0]
            + v4 * w4[0] + v5 * w5[0] + v6 * w6[0] + v7 * w7[0];
        a1 += v0 * w0[1] + v1 * w1[1] + v2 * w2[1] + v3 * w3[1]
            + v4 * w4[1] + v5 * w5[1] + v6 * w6[1] + v7 * w7[1];
        a2 += v0 * w0[2] + v1 * w1[2] + v2 * w2[2] + v3 * w3[2]
            + v4 * w4[2] + v5 * w5[2] + v6 * w6[2] + v7 * w7[2];
        a3 += v0 * w0[3] + v1 * w1[3] + v2 * w2[3] + v3 * w3[3]
            + v4 * w4[3] + v5 * w5[3] + v6 * w6[3] + v7 * w7[3];
    }
    float4 o = make_float4(a0, a1, a2, a3);
    *((float4*)(out + (size_t)n * OUT_DIM + og)) = o;
}

extern "C" void kernel_launch(void* const* d_in, const int* in_sizes, int n_in,
                              void* d_out, int out_size, void* d_ws, size_t ws_size,
                              hipStream_t stream) {
    const float* feat = (const float*)d_in[0];   // [50000,100]
    const float* W    = (const float*)d_in[1];   // [40,100]
    const float* b    = (const float*)d_in[2];   // [40]
    const int*   src  = (const int*)d_in[3];     // [800000]
    const int*   dst  = (const int*)d_in[4];     // [800000]
    float* out = (float*)d_out;                  // [50000,40]

    char* w = (char*)d_ws;
    int*   deg      = (int*)w;    w += N_NODES * 4;
    float* colsum   = (float*)w;  w += 128 * 4;
    float* colsq    = (float*)w;  w += 128 * 4;
    // ---- end of zero region: (N_NODES + 256) ints ----
    int*   eoff     = (int*)w;    w += N_EDGES * 4;
    int*   rowptr   = (int*)w;    w += 50004 * 4;
    float* norm     = (float*)w;  w += N_NODES * 4;
    float* norm2    = (float*)w;  w += N_NODES * 4;
    int*   blocksum = (int*)w;    w += 128 * 4;
    int*   csr      = (int*)w;    w += CSR_CAP * 4;
    // align row buffers to 256 B
    w = (char*)(((size_t)w + 255) & ~(size_t)255);
    const size_t HB = (size_t)(N_NODES + 1) * ROW_PAD * 4;   // padded rows + zero row
    uint*  fs       = (uint*)w;   w += HB;
    uint*  bufA     = (uint*)w;   w += HB;
    uint*  bufB     = (uint*)w;   w += HB;

    // 1. zero {deg, colsum, colsq} + zero pad-rows
    {
        int nz = N_NODES + 256;
        zero_kernel<<<(nz + 255) / 256, 256, 0, stream>>>(deg, nz, fs, bufA, bufB);
    }
    // 2. in-degree + per-edge slot (single atomic per edge total)
    deg_kernel<<<(N_EDGES + 255) / 256, 256, 0, stream>>>(dst, deg, eoff);
    // 3. rowptr over 8-aligned degrees + norm/norm2 (scan1), then merged
    //    offset-reduce + finalize + CSR pad fill (scan3)
    scan1_kernel<<<NSCAN_BLK, SCAN_B, 0, stream>>>(deg, rowptr, norm, norm2, blocksum);
    scan3_kernel<<<NSCAN_BLK, SCAN_B, 0, stream>>>(rowptr, blocksum, deg, csr);
    // 4. CSR scatter || prescale in one launch (independent work, overlapped)
    fill_prescale_kernel<<<CSRF_BLOCKS + PRE_BLOCKS, 256, 0, stream>>>(
        src, dst, rowptr, eoff, csr, feat, norm, (uint4*)fs);
    // 5. three hops: g1 = norm2*S(fs); g2 = norm2*S(g1); h3 = norm*S(g2)
    spmm_kernel<<<N_NODES / 2, 128, 0, stream>>>((const uint4*)fs, rowptr, csr, norm2, (uint4*)bufA);
    spmm_kernel<<<N_NODES / 2, 128, 0, stream>>>((const uint4*)bufA, rowptr, csr, norm2, (uint4*)bufB);
    spmm_kernel<<<N_NODES / 2, 128, 0, stream>>>((const uint4*)bufB, rowptr, csr, norm, (uint4*)bufA);
    // 6. column stats on padded bf16 h3
    col_stats_kernel<<<CS_BLOCKS, CS_THREADS, 0, stream>>>(bufA, colsum, colsq);
    // 7. final linear with fused standardize-fold
    {
        int total = N_NODES * 10;
        final_kernel<<<(total + 255) / 256, 256, 0, stream>>>(
            (const uint4*)bufA, colsum, colsq, W, b, out);
    }
}